// Round 1
// baseline (495.716 us; speedup 1.0000x reference)
//
#include <hip/hip_runtime.h>
#include <math.h>

#define Bq 2
#define Lq 2048
#define Eq 1024
#define Hq 16
#define Dq 64

typedef __attribute__((ext_vector_type(8))) short bf16x8;
typedef __attribute__((ext_vector_type(4))) float f32x4;

__device__ __forceinline__ short f2bf(float f) {
    union { float f; unsigned u; } x; x.f = f;
    unsigned r = x.u + 0x7FFFu + ((x.u >> 16) & 1u);
    return (short)(r >> 16);
}
__device__ __forceinline__ float bf2f(short s) {
    union { unsigned u; float f; } x;
    x.u = ((unsigned)(unsigned short)s) << 16;
    return x.f;
}
__device__ __forceinline__ bf16x8 pack8(float4 a, float4 b) {
    bf16x8 r;
    r[0] = f2bf(a.x); r[1] = f2bf(a.y); r[2] = f2bf(a.z); r[3] = f2bf(a.w);
    r[4] = f2bf(b.x); r[5] = f2bf(b.y); r[6] = f2bf(b.z); r[7] = f2bf(b.w);
    return r;
}

// out[tok, feat] = sum_e X[tok,e] * W[feat,e];  X:(4096,1024) W:(1024,1024) both f32 row-major.
// transposed==0: write bf16 to (B,H,L,D); transposed==1: write bf16 to (B,H,D,L).
__global__ __launch_bounds__(256) void proj_kernel(const float* __restrict__ X,
                                                   const float* __restrict__ W,
                                                   short* __restrict__ outb,
                                                   int transposed) {
    const int wave = threadIdx.x >> 6;
    const int lane = threadIdx.x & 63;
    const int l15 = lane & 15, quad = lane >> 4;
    const int m0 = blockIdx.x * 128 + (wave >> 1) * 64;  // token tile
    const int n0 = blockIdx.y * 128 + (wave & 1) * 64;   // feature tile
    f32x4 acc[4][4] = {};
    for (int e0 = 0; e0 < Eq; e0 += 32) {
        bf16x8 af[4], bfr[4];
#pragma unroll
        for (int i = 0; i < 4; ++i) {
            const float* px = X + (size_t)(m0 + i * 16 + l15) * Eq + e0 + quad * 8;
            af[i] = pack8(*(const float4*)px, *(const float4*)(px + 4));
            const float* pw = W + (size_t)(n0 + i * 16 + l15) * Eq + e0 + quad * 8;
            bfr[i] = pack8(*(const float4*)pw, *(const float4*)(pw + 4));
        }
#pragma unroll
        for (int i = 0; i < 4; ++i)
#pragma unroll
            for (int j = 0; j < 4; ++j)
                acc[i][j] = __builtin_amdgcn_mfma_f32_16x16x32_bf16(af[i], bfr[j], acc[i][j], 0, 0, 0);
    }
#pragma unroll
    for (int i = 0; i < 4; ++i) {
#pragma unroll
        for (int j = 0; j < 4; ++j) {
#pragma unroll
            for (int r = 0; r < 4; ++r) {
                int tok = m0 + i * 16 + quad * 4 + r;
                int feat = n0 + j * 16 + l15;
                int b = tok >> 11, l = tok & 2047;
                int h = feat >> 6, d = feat & 63;
                size_t idx = transposed
                                 ? (((size_t)(b * Hq + h) * Dq + d) * Lq + l)
                                 : (((size_t)(b * Hq + h) * Lq + l) * Dq + d);
                outb[idx] = f2bf(acc[i][j][r]);
            }
        }
    }
}

// x2[row] = sum_d bf2f(xb[row*64+d])^2 ; one wave per row, 4 rows per block
__global__ __launch_bounds__(256) void sumsq_kernel(const short* __restrict__ xb,
                                                    float* __restrict__ x2) {
    int row = blockIdx.x * 4 + (threadIdx.x >> 6);
    int lane = threadIdx.x & 63;
    float v = bf2f(xb[(size_t)row * 64 + lane]);
    float s = v * v;
#pragma unroll
    for (int off = 1; off < 64; off <<= 1) s += __shfl_xor(s, off);
    if (lane == 0) x2[row] = s;
}

__global__ void zero_kernel(float* __restrict__ p, int n) {
    int i = blockIdx.x * 256 + threadIdx.x;
    if (i < n) p[i] = 0.f;
}

// Flash attention with scores = -||q-k||, plus reduction over query rows into osum (B,H,D).
// qb,kb: (B,H,L,D) bf16 ; vT: (B,H,D,L) bf16 ; q2,k2: (B,H,L) f32.
__global__ __launch_bounds__(256) void flash_kernel(const short* __restrict__ qb,
                                                    const short* __restrict__ kb,
                                                    const short* __restrict__ vT,
                                                    const float* __restrict__ q2,
                                                    const float* __restrict__ k2,
                                                    float* __restrict__ osum) {
    const int wave = threadIdx.x >> 6;
    const int lane = threadIdx.x & 63;
    const int l15 = lane & 15, quad = lane >> 4;
    const int bh = blockIdx.y;
    const int q0 = blockIdx.x * 128 + wave * 32;  // 32 query rows per wave
    const short* qbh = qb + (size_t)bh * Lq * Dq;
    const short* kbh = kb + (size_t)bh * Lq * Dq;
    const short* vbh = vT + (size_t)bh * Dq * Lq;
    const float* q2h = q2 + (size_t)bh * Lq;
    const float* k2h = k2 + (size_t)bh * Lq;

    // per-wave P round-trip buffers: 2 tiles of 16x32, row stride 40 (pad vs bank conflicts)
    __shared__ __align__(16) short plds[4][2][16 * 40];

    bf16x8 qf[2][2];
    float q2r[2][4];
#pragma unroll
    for (int t = 0; t < 2; ++t) {
        const short* p = qbh + (size_t)(q0 + t * 16 + l15) * Dq + quad * 8;
        qf[t][0] = *(const bf16x8*)p;
        qf[t][1] = *(const bf16x8*)(p + 32);
#pragma unroll
        for (int r = 0; r < 4; ++r) q2r[t][r] = q2h[q0 + t * 16 + quad * 4 + r];
    }
    f32x4 o[2][4] = {};
    float m[2][4], lsum[2][4];
#pragma unroll
    for (int t = 0; t < 2; ++t)
#pragma unroll
        for (int r = 0; r < 4; ++r) { m[t][r] = -1e30f; lsum[t][r] = 0.f; }

    for (int k0 = 0; k0 < Lq; k0 += 32) {
        bf16x8 kf[2][2], vf[4];
        float k2c[2];
#pragma unroll
        for (int kt = 0; kt < 2; ++kt) {
            const short* p = kbh + (size_t)(k0 + kt * 16 + l15) * Dq + quad * 8;
            kf[kt][0] = *(const bf16x8*)p;
            kf[kt][1] = *(const bf16x8*)(p + 32);
            k2c[kt] = k2h[k0 + kt * 16 + l15];
        }
#pragma unroll
        for (int f = 0; f < 4; ++f) {
            const short* p = vbh + (size_t)(f * 16 + l15) * Lq + k0 + quad * 8;
            vf[f] = *(const bf16x8*)p;
        }
#pragma unroll
        for (int t = 0; t < 2; ++t) {
            f32x4 s0 = {0.f, 0.f, 0.f, 0.f}, s1 = {0.f, 0.f, 0.f, 0.f};
            s0 = __builtin_amdgcn_mfma_f32_16x16x32_bf16(qf[t][0], kf[0][0], s0, 0, 0, 0);
            s0 = __builtin_amdgcn_mfma_f32_16x16x32_bf16(qf[t][1], kf[0][1], s0, 0, 0, 0);
            s1 = __builtin_amdgcn_mfma_f32_16x16x32_bf16(qf[t][0], kf[1][0], s1, 0, 0, 0);
            s1 = __builtin_amdgcn_mfma_f32_16x16x32_bf16(qf[t][1], kf[1][1], s1, 0, 0, 0);
            float sc[2][4];
#pragma unroll
            for (int r = 0; r < 4; ++r) {
                sc[0][r] = -sqrtf(fmaxf(q2r[t][r] + k2c[0] - 2.f * s0[r], 0.f));
                sc[1][r] = -sqrtf(fmaxf(q2r[t][r] + k2c[1] - 2.f * s1[r], 0.f));
            }
            float cm[4];
#pragma unroll
            for (int r = 0; r < 4; ++r) cm[r] = fmaxf(sc[0][r], sc[1][r]);
#pragma unroll
            for (int off = 1; off < 16; off <<= 1)
#pragma unroll
                for (int r = 0; r < 4; ++r) cm[r] = fmaxf(cm[r], __shfl_xor(cm[r], off));
            float alpha[4], ps[4];
#pragma unroll
            for (int r = 0; r < 4; ++r) {
                float mn = fmaxf(m[t][r], cm[r]);
                alpha[r] = __expf(m[t][r] - mn);
                m[t][r] = mn;
                float p0 = __expf(sc[0][r] - mn);
                float p1 = __expf(sc[1][r] - mn);
                sc[0][r] = p0; sc[1][r] = p1;
                ps[r] = p0 + p1;
            }
#pragma unroll
            for (int off = 1; off < 16; off <<= 1)
#pragma unroll
                for (int r = 0; r < 4; ++r) ps[r] += __shfl_xor(ps[r], off);
#pragma unroll
            for (int r = 0; r < 4; ++r) lsum[t][r] = lsum[t][r] * alpha[r] + ps[r];
#pragma unroll
            for (int f = 0; f < 4; ++f)
#pragma unroll
                for (int r = 0; r < 4; ++r) o[t][f][r] *= alpha[r];
            // C-layout -> A-layout transpose through wave-private LDS
            short* pl = &plds[wave][t][0];
#pragma unroll
            for (int kt = 0; kt < 2; ++kt)
#pragma unroll
                for (int r = 0; r < 4; ++r)
                    pl[(quad * 4 + r) * 40 + kt * 16 + l15] = f2bf(sc[kt][r]);
            asm volatile("s_waitcnt lgkmcnt(0)" ::: "memory");
            bf16x8 pa = *(const bf16x8*)(pl + l15 * 40 + quad * 8);
#pragma unroll
            for (int f = 0; f < 4; ++f)
                o[t][f] = __builtin_amdgcn_mfma_f32_16x16x32_bf16(pa, vf[f], o[t][f], 0, 0, 0);
        }
    }
    // normalize rows by lsum, reduce over the 32 query rows, atomically add to osum
#pragma unroll
    for (int t = 0; t < 2; ++t) {
#pragma unroll
        for (int f = 0; f < 4; ++f) {
            float cs = 0.f;
#pragma unroll
            for (int r = 0; r < 4; ++r) cs += o[t][f][r] / lsum[t][r];
            cs += __shfl_xor(cs, 16);
            cs += __shfl_xor(cs, 32);
            if (quad == 0) atomicAdd(&osum[(size_t)bh * Dq + f * 16 + l15], cs);
        }
    }
}

// out[b,j] = sum_e osum[b,e] * Wo[j,e]; one wave per output element
__global__ __launch_bounds__(256) void outproj_kernel(const float* __restrict__ osum,
                                                      const float* __restrict__ Wo,
                                                      float* __restrict__ out) {
    int idx = blockIdx.x * 4 + (threadIdx.x >> 6);
    int lane = threadIdx.x & 63;
    int b = idx >> 10, j = idx & 1023;
    const float* o = osum + (size_t)b * Eq;
    const float* w = Wo + (size_t)j * Eq;
    float4 s4 = {0.f, 0.f, 0.f, 0.f};
    for (int e = lane * 4; e < Eq; e += 256) {
        float4 ov = *(const float4*)(o + e);
        float4 wv = *(const float4*)(w + e);
        s4.x += ov.x * wv.x; s4.y += ov.y * wv.y;
        s4.z += ov.z * wv.z; s4.w += ov.w * wv.w;
    }
    float s = s4.x + s4.y + s4.z + s4.w;
#pragma unroll
    for (int off = 1; off < 64; off <<= 1) s += __shfl_xor(s, off);
    if (lane == 0) out[idx] = s;
}

extern "C" void kernel_launch(void* const* d_in, const int* in_sizes, int n_in,
                              void* d_out, int out_size, void* d_ws, size_t ws_size,
                              hipStream_t stream) {
    const float* Q  = (const float*)d_in[0];
    const float* K  = (const float*)d_in[1];
    const float* V  = (const float*)d_in[2];
    const float* Wq = (const float*)d_in[3];
    const float* Wk = (const float*)d_in[4];
    const float* Wv = (const float*)d_in[5];
    const float* Wo = (const float*)d_in[6];
    float* out = (float*)d_out;

    char* ws = (char*)d_ws;
    short* qb = (short*)(ws);                       // 8 MB  (B,H,L,D) bf16
    short* kb = (short*)(ws + (size_t)(8 << 20));   // 8 MB  (B,H,L,D) bf16
    short* vT = (short*)(ws + (size_t)(16 << 20));  // 8 MB  (B,H,D,L) bf16
    float* q2 = (float*)(ws + (size_t)(24 << 20));                  // 256 KB
    float* k2 = (float*)(ws + (size_t)(24 << 20) + (256 << 10));    // 256 KB
    float* os = (float*)(ws + (size_t)(24 << 20) + (512 << 10));    // 8 KB

    dim3 pgrid(32, 8);
    proj_kernel<<<pgrid, 256, 0, stream>>>(Q, Wq, qb, 0);
    proj_kernel<<<pgrid, 256, 0, stream>>>(K, Wk, kb, 0);
    proj_kernel<<<pgrid, 256, 0, stream>>>(V, Wv, vT, 1);
    sumsq_kernel<<<16384, 256, 0, stream>>>(qb, q2);
    sumsq_kernel<<<16384, 256, 0, stream>>>(kb, k2);
    zero_kernel<<<8, 256, 0, stream>>>(os, Bq * Eq);
    flash_kernel<<<dim3(16, 32), 256, 0, stream>>>(qb, kb, vT, q2, k2, os);
    outproj_kernel<<<512, 256, 0, stream>>>(os, Wo, out);
}

// Round 3
// 486.549 us; speedup vs baseline: 1.0188x; 1.0188x over previous
//
#include <hip/hip_runtime.h>
#include <math.h>

#define Bq 2
#define Lq 2048
#define Eq 1024
#define Hq 16
#define Dq 64

typedef __attribute__((ext_vector_type(8))) short bf16x8;
typedef __attribute__((ext_vector_type(4))) short bf16x4;
typedef __attribute__((ext_vector_type(4))) float f32x4;

__device__ __forceinline__ short f2bf(float f) {
    union { float f; unsigned u; } x; x.f = f;
    unsigned r = x.u + 0x7FFFu + ((x.u >> 16) & 1u);
    return (short)(r >> 16);
}
__device__ __forceinline__ float bf2f(short s) {
    union { unsigned u; float f; } x;
    x.u = ((unsigned)(unsigned short)s) << 16;
    return x.f;
}

// Cast Q,K,V (4096x1024 f32) and Wq,Wk,Wv (1024x1024 f32) to bf16, laid out
// consecutively in `out`: [Xq | Xk | Xv | Wqb | Wkb | Wvb].
__global__ __launch_bounds__(256) void cast_all(const float* __restrict__ Q,
                                                const float* __restrict__ K,
                                                const float* __restrict__ V,
                                                const float* __restrict__ Wq,
                                                const float* __restrict__ Wk,
                                                const float* __restrict__ Wv,
                                                short* __restrict__ out) {
    const size_t NX = (size_t)4096 * 1024 / 4;  // float4 count per X
    const size_t NW = (size_t)1024 * 1024 / 4;  // float4 count per W
    size_t id = (size_t)blockIdx.x * 256 + threadIdx.x;
    const float* src; size_t off;
    if (id < NX)              { src = Q;  off = id; }
    else if (id < 2 * NX)     { src = K;  off = id - NX; }
    else if (id < 3 * NX)     { src = V;  off = id - 2 * NX; }
    else if (id < 3 * NX + NW)     { src = Wq; off = id - 3 * NX; }
    else if (id < 3 * NX + 2 * NW) { src = Wk; off = id - 3 * NX - NW; }
    else                           { src = Wv; off = id - 3 * NX - 2 * NW; }
    float4 v = ((const float4*)src)[off];
    bf16x4 s;
    s[0] = f2bf(v.x); s[1] = f2bf(v.y); s[2] = f2bf(v.z); s[3] = f2bf(v.w);
    ((bf16x4*)out)[id] = s;
}

// out[tok,feat] = sum_e Xb[tok,e] * Wb[feat,e]; bf16 inputs, fp32 accum, bf16 out.
// transposed==0: (B,H,L,D) layout; ==1: (B,H,D,L).
// If x2 != nullptr, also writes per-(b,h,l) sum of squares of the bf16-rounded outputs.
// Block tile 64(M)x128(N), wave tile 32x64 => wave's N range is exactly one head.
__global__ __launch_bounds__(256) void proj_kernel(const short* __restrict__ Xb,
                                                   const short* __restrict__ Wb,
                                                   short* __restrict__ outb,
                                                   float* __restrict__ x2,
                                                   int transposed) {
    const int wave = threadIdx.x >> 6;
    const int lane = threadIdx.x & 63;
    const int l15 = lane & 15, quad = lane >> 4;
    const int m0 = blockIdx.x * 64 + (wave & 1) * 32;
    const int n0 = blockIdx.y * 128 + (wave >> 1) * 64;
    f32x4 acc[2][4] = {};
    for (int e0 = 0; e0 < Eq; e0 += 32) {
        bf16x8 af[2], bfr[4];
#pragma unroll
        for (int i = 0; i < 2; ++i)
            af[i] = *(const bf16x8*)(Xb + (size_t)(m0 + i * 16 + l15) * Eq + e0 + quad * 8);
#pragma unroll
        for (int j = 0; j < 4; ++j)
            bfr[j] = *(const bf16x8*)(Wb + (size_t)(n0 + j * 16 + l15) * Eq + e0 + quad * 8);
#pragma unroll
        for (int i = 0; i < 2; ++i)
#pragma unroll
            for (int j = 0; j < 4; ++j)
                acc[i][j] = __builtin_amdgcn_mfma_f32_16x16x32_bf16(af[i], bfr[j], acc[i][j], 0, 0, 0);
    }
    const int h = n0 >> 6;
#pragma unroll
    for (int i = 0; i < 2; ++i) {
        float ss[4] = {0.f, 0.f, 0.f, 0.f};
#pragma unroll
        for (int r = 0; r < 4; ++r) {
            int tok = m0 + i * 16 + quad * 4 + r;
            int b = tok >> 11, l = tok & 2047;
#pragma unroll
            for (int j = 0; j < 4; ++j) {
                int feat = n0 + j * 16 + l15;
                int d = feat & 63;
                short sb = f2bf(acc[i][j][r]);
                float sv = bf2f(sb);
                ss[r] += sv * sv;
                size_t idx = transposed
                                 ? (((size_t)(b * Hq + h) * Dq + d) * Lq + l)
                                 : (((size_t)(b * Hq + h) * Lq + l) * Dq + d);
                outb[idx] = sb;
            }
        }
        if (x2 != nullptr) {
#pragma unroll
            for (int r = 0; r < 4; ++r) {
#pragma unroll
                for (int off = 1; off < 16; off <<= 1) ss[r] += __shfl_xor(ss[r], off);
            }
            if (l15 == 0) {
#pragma unroll
                for (int r = 0; r < 4; ++r) {
                    int tok = m0 + i * 16 + quad * 4 + r;
                    int b = tok >> 11, l = tok & 2047;
                    x2[(size_t)(b * Hq + h) * Lq + l] = ss[r];
                }
            }
        }
    }
}

__global__ void zero_kernel(float* __restrict__ p, int n) {
    int i = blockIdx.x * 256 + threadIdx.x;
    if (i < n) p[i] = 0.f;
}

// Flash attention, scores = -||q-k||. Fixed softmax max = 0 (scores <= 0 always),
// so no running max / rescale / per-chunk cross-lane reductions.
// 16 q-rows per wave, 64 per block; grid (32, B*H).
__global__ __launch_bounds__(256) void flash_kernel(const short* __restrict__ qb,
                                                    const short* __restrict__ kb,
                                                    const short* __restrict__ vT,
                                                    const float* __restrict__ q2,
                                                    const float* __restrict__ k2,
                                                    float* __restrict__ osum) {
    const int wave = threadIdx.x >> 6;
    const int lane = threadIdx.x & 63;
    const int l15 = lane & 15, quad = lane >> 4;
    const int bh = blockIdx.y;
    const int q0 = blockIdx.x * 64 + wave * 16;
    const short* qbh = qb + (size_t)bh * Lq * Dq;
    const short* kbh = kb + (size_t)bh * Lq * Dq;
    const short* vbh = vT + (size_t)bh * Dq * Lq;
    const float* q2h = q2 + (size_t)bh * Lq;
    const float* k2h = k2 + (size_t)bh * Lq;

    // per-wave P transpose buffer: 16 rows x 32 cols, row stride 56 shorts (112B, 16B-aligned)
    __shared__ __align__(16) short plds[4][16 * 56];
    short* pl = plds[wave];

    const short* qp = qbh + (size_t)(q0 + l15) * Dq + quad * 8;
    bf16x8 qf0 = *(const bf16x8*)qp;
    bf16x8 qf1 = *(const bf16x8*)(qp + 32);
    float q2r[4];
#pragma unroll
    for (int r = 0; r < 4; ++r) q2r[r] = q2h[q0 + quad * 4 + r];

    f32x4 o[4] = {};
    float lsum[4] = {0.f, 0.f, 0.f, 0.f};

    for (int k0 = 0; k0 < Lq; k0 += 32) {
        const short* kp = kbh + (size_t)(k0 + l15) * Dq + quad * 8;
        bf16x8 kf00 = *(const bf16x8*)kp;
        bf16x8 kf01 = *(const bf16x8*)(kp + 32);
        bf16x8 kf10 = *(const bf16x8*)(kp + 16 * Dq);
        bf16x8 kf11 = *(const bf16x8*)(kp + 16 * Dq + 32);
        bf16x8 vf[4];
#pragma unroll
        for (int f = 0; f < 4; ++f)
            vf[f] = *(const bf16x8*)(vbh + (size_t)(f * 16 + l15) * Lq + k0 + quad * 8);
        float k2c0 = k2h[k0 + l15];
        float k2c1 = k2h[k0 + 16 + l15];

        f32x4 s0 = {0.f, 0.f, 0.f, 0.f}, s1 = {0.f, 0.f, 0.f, 0.f};
        s0 = __builtin_amdgcn_mfma_f32_16x16x32_bf16(qf0, kf00, s0, 0, 0, 0);
        s0 = __builtin_amdgcn_mfma_f32_16x16x32_bf16(qf1, kf01, s0, 0, 0, 0);
        s1 = __builtin_amdgcn_mfma_f32_16x16x32_bf16(qf0, kf10, s1, 0, 0, 0);
        s1 = __builtin_amdgcn_mfma_f32_16x16x32_bf16(qf1, kf11, s1, 0, 0, 0);

#pragma unroll
        for (int r = 0; r < 4; ++r) {
            float d0 = fmaxf(q2r[r] + k2c0 - 2.f * s0[r], 0.f);
            float d1 = fmaxf(q2r[r] + k2c1 - 2.f * s1[r], 0.f);
            float p0 = __expf(-__builtin_amdgcn_sqrtf(d0));
            float p1 = __expf(-__builtin_amdgcn_sqrtf(d1));
            lsum[r] += p0 + p1;
            pl[(quad * 4 + r) * 56 + l15] = f2bf(p0);
            pl[(quad * 4 + r) * 56 + 16 + l15] = f2bf(p1);
        }
        asm volatile("s_waitcnt lgkmcnt(0)" ::: "memory");
        bf16x8 pa = *(const bf16x8*)(pl + l15 * 56 + quad * 8);
#pragma unroll
        for (int f = 0; f < 4; ++f)
            o[f] = __builtin_amdgcn_mfma_f32_16x16x32_bf16(pa, vf[f], o[f], 0, 0, 0);
    }

    // one cross-lane reduction of lsum at the end (over the 16 cols = l15 lanes)
#pragma unroll
    for (int r = 0; r < 4; ++r) {
#pragma unroll
        for (int off = 1; off < 16; off <<= 1) lsum[r] += __shfl_xor(lsum[r], off);
    }
#pragma unroll
    for (int f = 0; f < 4; ++f) {
        float cs = o[f][0] / lsum[0] + o[f][1] / lsum[1] + o[f][2] / lsum[2] + o[f][3] / lsum[3];
        cs += __shfl_xor(cs, 16);
        cs += __shfl_xor(cs, 32);
        if (quad == 0) atomicAdd(&osum[(size_t)bh * Dq + f * 16 + l15], cs);
    }
}

// out[b,j] = sum_e osum[b,e] * Wo[j,e]; one wave per output element
__global__ __launch_bounds__(256) void outproj_kernel(const float* __restrict__ osum,
                                                      const float* __restrict__ Wo,
                                                      float* __restrict__ out) {
    int idx = blockIdx.x * 4 + (threadIdx.x >> 6);
    int lane = threadIdx.x & 63;
    int b = idx >> 10, j = idx & 1023;
    const float* o = osum + (size_t)b * Eq;
    const float* w = Wo + (size_t)j * Eq;
    float4 s4 = {0.f, 0.f, 0.f, 0.f};
    for (int e = lane * 4; e < Eq; e += 256) {
        float4 ov = *(const float4*)(o + e);
        float4 wv = *(const float4*)(w + e);
        s4.x += ov.x * wv.x; s4.y += ov.y * wv.y;
        s4.z += ov.z * wv.z; s4.w += ov.w * wv.w;
    }
    float s = s4.x + s4.y + s4.z + s4.w;
#pragma unroll
    for (int off = 1; off < 64; off <<= 1) s += __shfl_xor(s, off);
    if (lane == 0) out[idx] = s;
}

extern "C" void kernel_launch(void* const* d_in, const int* in_sizes, int n_in,
                              void* d_out, int out_size, void* d_ws, size_t ws_size,
                              hipStream_t stream) {
    const float* Q  = (const float*)d_in[0];
    const float* K  = (const float*)d_in[1];
    const float* V  = (const float*)d_in[2];
    const float* Wq = (const float*)d_in[3];
    const float* Wk = (const float*)d_in[4];
    const float* Wv = (const float*)d_in[5];
    const float* Wo = (const float*)d_in[6];
    float* out = (float*)d_out;

    char* ws = (char*)d_ws;
    // cast area: Xq,Xk,Xv (8 MB each) + Wqb,Wkb,Wvb (2 MB each) = 30 MB, consecutive
    short* castb = (short*)ws;
    short* Xqb = castb;
    short* Xkb = castb + (size_t)4194304;
    short* Xvb = castb + (size_t)2 * 4194304;
    short* Wqb = castb + (size_t)3 * 4194304;
    short* Wkb = Wqb + (size_t)1048576;
    short* Wvb = Wqb + (size_t)2 * 1048576;
    char* p = ws + (size_t)(30 << 20);
    short* qb = (short*)p;                       // 8 MB (B,H,L,D)
    short* kb = (short*)(p + (size_t)(8 << 20)); // 8 MB (B,H,L,D)
    short* vT = (short*)(p + (size_t)(16 << 20));// 8 MB (B,H,D,L)
    float* q2 = (float*)(p + (size_t)(24 << 20));                 // 256 KB
    float* k2 = (float*)(p + (size_t)(24 << 20) + (256 << 10));   // 256 KB
    float* os = (float*)(p + (size_t)(24 << 20) + (512 << 10));   // 8 KB

    cast_all<<<15360, 256, 0, stream>>>(Q, K, V, Wq, Wk, Wv, castb);
    dim3 pgrid(64, 8);
    proj_kernel<<<pgrid, 256, 0, stream>>>(Xqb, Wqb, qb, q2, 0);
    proj_kernel<<<pgrid, 256, 0, stream>>>(Xkb, Wkb, kb, k2, 0);
    proj_kernel<<<pgrid, 256, 0, stream>>>(Xvb, Wvb, vT, nullptr, 1);
    zero_kernel<<<8, 256, 0, stream>>>(os, Bq * Eq);
    flash_kernel<<<dim3(32, 32), 256, 0, stream>>>(qb, kb, vT, q2, k2, os);
    outproj_kernel<<<512, 256, 0, stream>>>(os, Wo, out);
}